// Round 9
// baseline (348.810 us; speedup 1.0000x reference)
//
#include <hip/hip_runtime.h>

// Chamfer via MFMA v5: in-register packing both sides, no LDS, no tables.
// Per 64-thread block (1 wave): 128 fixed F-columns (4 B-frags w/ -2 factors
// built once) x stream S-rows 32/step. d2 = s2 + f2 - 2 s.f via K=16 bf16
// hi/lo split (scheme algebra verified absmax 0.0 in R3/R6/R8).
// Min over rows = register min3-trees, software-pipelined against MFMAs.

typedef __attribute__((ext_vector_type(8)))  short    bf16x8;
typedef __attribute__((ext_vector_type(16))) float    f32x16;
typedef __attribute__((ext_vector_type(4)))  unsigned uint32x4;

constexpr int NPTS   = 8192;
constexpr int COLS_W = 128;              // F-columns per wave (4 B-frags)
constexpr int N_MG   = NPTS / COLS_W;    // 64 column groups
constexpr int NSPLIT = 16;               // streamed-row split
constexpr int SROWS  = NPTS / NSPLIT;    // 512 rows per wave
constexpr int STEPS  = SROWS / 32;       // 16 steps

__device__ inline float hi16f(float f) {           // truncation split (exact lo)
    return __uint_as_float(__float_as_uint(f) & 0xFFFF0000u);
}
// dword = bf16(hi_src)<<16 | bf16(lo_src)  (1x v_perm_b32, truncating)
__device__ inline unsigned pack2(float lo_src, float hi_src) {
    return __builtin_amdgcn_perm(__float_as_uint(hi_src),
                                 __float_as_uint(lo_src), 0x07060302u);
}

__global__ __launch_bounds__(64, 4) void chamfer_v5(
    const float* __restrict__ pred, const float* __restrict__ targ,
    float* __restrict__ part)
{
    const int lane = threadIdx.x;
    const int l31  = lane & 31;
    const int g    = lane >> 5;          // k-group: 0 -> k0-7, 1 -> k8-15
    const int mg   = blockIdx.x;         // 0..63  column group
    const int ns   = blockIdx.y;         // 0..15  row split
    const int db   = blockIdx.z;         // dir = db&1, b = db>>1
    const int dir  = db & 1, b = db >> 1;

    const float* F = (dir ? targ : pred) + (size_t)b * 3 * NPTS;
    const float* S = (dir ? pred : targ) + (size_t)b * 3 * NPTS;
    const unsigned ONE2 = 0x3F803F80u;   // bf16 1.0 | 1.0

    // ---- fixed side: 4 B-frags, -2 factors live here (built once) ----
    // B k-scheme g0: [1, 1, f2h, f2l, m2xh, m2xl, m2xh, m2yh]
    //            g1: [m2yl, m2yh, m2zh, m2zl, m2zh, 0, 0, 0]
    auto build_bf = [&](int j) -> bf16x8 {
        int c = mg * COLS_W + j * 32 + l31;
        float x = F[c], y = F[NPTS + c], z = F[2 * NPTS + c];
        float f2  = fmaf(x, x, fmaf(y, y, z * z));
        float m2x = -2.f * x, m2y = -2.f * y, m2z = -2.f * z;
        uint32x4 d;
        if (g == 0) {
            float f2l  = f2  - hi16f(f2);
            float m2xl = m2x - hi16f(m2x);
            d[0] = ONE2;
            d[1] = pack2(f2, f2l);
            d[2] = pack2(m2x, m2xl);
            d[3] = pack2(m2x, m2y);
        } else {
            float m2yl = m2y - hi16f(m2y);
            float m2zl = m2z - hi16f(m2z);
            d[0] = pack2(m2yl, m2y);
            d[1] = pack2(m2z, m2zl);
            d[2] = pack2(m2z, 0.f);
            d[3] = 0u;
        }
        return __builtin_bit_cast(bf16x8, d);
    };
    bf16x8 bf0 = build_bf(0), bf1 = build_bf(1);
    bf16x8 bf2 = build_bf(2), bf3 = build_bf(3);

    // A k-scheme g0: [s2h, s2l, 1, 1, xh, xh, xl, yh]
    //            g1: [yh, yl, zh, zh, zl, 0, 0, 0]
    auto build_af = [&](float x, float y, float z) -> bf16x8 {
        float s2 = fmaf(x, x, fmaf(y, y, z * z));
        uint32x4 d;
        if (g == 0) {
            float s2l = s2 - hi16f(s2);
            float xl  = x  - hi16f(x);
            d[0] = pack2(s2, s2l);
            d[1] = ONE2;
            d[2] = pack2(x, x);
            d[3] = pack2(xl, y);
        } else {
            float yl = y - hi16f(y);
            float zl = z - hi16f(z);
            d[0] = pack2(y, yl);
            d[1] = pack2(z, z);
            d[2] = pack2(zl, 0.f);
            d[3] = 0u;
        }
        return __builtin_bit_cast(bf16x8, d);
    };

    f32x16 zero;
    #pragma unroll
    for (int i = 0; i < 16; ++i) zero[i] = 0.f;

    const float INF = __int_as_float(0x7F800000);
    float a0 = INF, a1 = INF, a2 = INF, a3 = INF;

    // min over the 16 regs (= 16 rows) into a per-column scalar: 8x v_min3
    auto tree = [](float acc, const f32x16& c) -> float {
        float t0 = fminf(fminf(c[0],  c[1]),  c[2]);
        float t1 = fminf(fminf(c[3],  c[4]),  c[5]);
        float t2 = fminf(fminf(c[6],  c[7]),  c[8]);
        float t3 = fminf(fminf(c[9],  c[10]), c[11]);
        float t4 = fminf(fminf(c[12], c[13]), c[14]);
        float r0 = fminf(fminf(t0, t1), t2);
        float r1 = fminf(fminf(t3, t4), c[15]);
        return fminf(fminf(r0, r1), acc);
    };

    const float* S0 = S + (size_t)ns * SROWS + l31;
    const float* S1 = S0 + NPTS;
    const float* S2 = S0 + 2 * NPTS;

    float cx = S0[0], cy = S1[0], cz = S2[0];
    #pragma unroll 4
    for (int s = 0; s < STEPS; ++s) {
        float nx = 0.f, ny = 0.f, nz = 0.f;
        if (s + 1 < STEPS) {                 // wave-uniform branch
            int o = (s + 1) * 32;
            nx = S0[o]; ny = S1[o]; nz = S2[o];
        }
        bf16x8 af = build_af(cx, cy, cz);
        // software-pipelined consumption: >=2 trees + 1 MFMA between an
        // MFMA's issue and the first read of its result
        f32x16 c0 = __builtin_amdgcn_mfma_f32_32x32x16_bf16(af, bf0, zero, 0, 0, 0);
        f32x16 c1 = __builtin_amdgcn_mfma_f32_32x32x16_bf16(af, bf1, zero, 0, 0, 0);
        a0 = tree(a0, c0);
        c0 = __builtin_amdgcn_mfma_f32_32x32x16_bf16(af, bf2, zero, 0, 0, 0);
        a1 = tree(a1, c1);
        c1 = __builtin_amdgcn_mfma_f32_32x32x16_bf16(af, bf3, zero, 0, 0, 0);
        a2 = tree(a2, c0);
        a3 = tree(a3, c1);
        cx = nx; cy = ny; cz = nz;
    }

    // combine lane-halves (g=0 regs hold rows {..}, g=1 the complementary 16)
    a0 = fminf(a0, __shfl_xor(a0, 32));
    a1 = fminf(a1, __shfl_xor(a1, 32));
    a2 = fminf(a2, __shfl_xor(a2, 32));
    a3 = fminf(a3, __shfl_xor(a3, 32));

    if (lane < 32) {
        float* dst = part + ((size_t)db * NSPLIT + ns) * NPTS + (size_t)mg * COLS_W;
        dst[l31]      = a0;
        dst[32 + l31] = a1;
        dst[64 + l31] = a2;
        dst[96 + l31] = a3;
    }
}

// min over NSPLIT partials, sqrt, mean, sum both directions
__global__ __launch_bounds__(256) void reduce_k(
    const float* __restrict__ part, float* __restrict__ out)
{
    int tid = blockIdx.x * 256 + threadIdx.x;   // 0..65535
    int db  = tid >> 13;
    int m   = tid & (NPTS - 1);
    const float* base = part + (size_t)db * NSPLIT * NPTS + m;
    float v = base[0];
    #pragma unroll
    for (int nsh = 1; nsh < NSPLIT; ++nsh)
        v = fminf(v, base[(size_t)nsh * NPTS]);
    float d = sqrtf(fmaxf(v, 0.f)) * (1.0f / 32768.0f);
    for (int off = 32; off; off >>= 1) d += __shfl_down(d, off);
    __shared__ float wsum[4];
    if ((threadIdx.x & 63) == 0) wsum[threadIdx.x >> 6] = d;
    __syncthreads();
    if (threadIdx.x == 0) atomicAdd(out, wsum[0] + wsum[1] + wsum[2] + wsum[3]);
}

extern "C" void kernel_launch(void* const* d_in, const int* in_sizes, int n_in,
                              void* d_out, int out_size, void* d_ws, size_t ws_size,
                              hipStream_t stream) {
    const float* pred = (const float*)d_in[0];
    const float* targ = (const float*)d_in[1];
    float* out  = (float*)d_out;
    float* part = (float*)d_ws;   // 8 * NSPLIT * NPTS * 4 = 4 MB

    hipMemsetAsync(d_out, 0, sizeof(float), stream);

    dim3 grid(N_MG, NSPLIT, 8);   // 64 x 16 x 8 = 8192 one-wave blocks
    chamfer_v5<<<grid, 64, 0, stream>>>(pred, targ, part);

    reduce_k<<<(8 * NPTS) / 256, 256, 0, stream>>>(part, out);
}

// Round 10
// 80.852 us; speedup vs baseline: 4.3142x; 4.3142x over previous
//
#include <hip/hip_runtime.h>

// Chamfer via MFMA v6: v5's 128-cols/wave economics on v3's proven codegen
// config (256-thread blocks, bounds(256,4), <=2 live C-tiles, no unroll).
// d2 = s2 + f2 - 2 s.f via K=16 bf16 hi/lo split (absmax 0.0 in R3/R6/R8/R9).
// Min over streamed rows = register min3-trees; partial col-mins to ws;
// tiny reduce kernel does min/sqrt/mean/atomicAdd.

typedef __attribute__((ext_vector_type(8)))  short    bf16x8;
typedef __attribute__((ext_vector_type(16))) float    f32x16;
typedef __attribute__((ext_vector_type(4)))  unsigned uint32x4;

constexpr int NPTS   = 8192;
constexpr int COLS_W = 128;               // F-columns per wave (4 B-frags)
constexpr int COLS_B = COLS_W * 4;        // 512 cols per 4-wave block
constexpr int N_CG   = NPTS / COLS_B;     // 16 column groups (blockIdx.x)
constexpr int NSPLIT = 8;                 // streamed-row split
constexpr int SROWS  = NPTS / NSPLIT;     // 1024 rows per wave
constexpr int STEPS  = SROWS / 32;        // 32 steps

__device__ inline float hi16f(float f) {            // truncation split (exact lo)
    return __uint_as_float(__float_as_uint(f) & 0xFFFF0000u);
}
// dword = bf16(hi_src)<<16 | bf16(lo_src)  (1x v_perm_b32, truncating)
__device__ inline unsigned pack2(float lo_src, float hi_src) {
    return __builtin_amdgcn_perm(__float_as_uint(hi_src),
                                 __float_as_uint(lo_src), 0x07060302u);
}

__global__ __launch_bounds__(256, 4) void chamfer_v6(
    const float* __restrict__ pred, const float* __restrict__ targ,
    float* __restrict__ part)
{
    const int lane = threadIdx.x & 63;
    const int wv   = threadIdx.x >> 6;
    const int l31  = lane & 31;
    const int g    = lane >> 5;           // k-group: 0 -> k0-7, 1 -> k8-15
    const int mg   = blockIdx.x * 4 + wv; // 0..63 column group (128 cols)
    const int ns   = blockIdx.y;          // 0..NSPLIT-1
    const int db   = blockIdx.z;          // dir = db&1, b = db>>1
    const int dir  = db & 1, b = db >> 1;

    const float* F = (dir ? targ : pred) + (size_t)b * 3 * NPTS;
    const float* S = (dir ? pred : targ) + (size_t)b * 3 * NPTS;
    const unsigned ONE2 = 0x3F803F80u;    // bf16 1.0 | 1.0

    // ---- fixed side: 4 B-frags, -2 factors live here (built once) ----
    // B k-scheme g0: [1, 1, f2h, f2l, m2xh, m2xl, m2xh, m2yh]
    //            g1: [m2yl, m2yh, m2zh, m2zl, m2zh, 0, 0, 0]
    auto build_bf = [&](int j) -> bf16x8 {
        int c = mg * COLS_W + j * 32 + l31;
        float x = F[c], y = F[NPTS + c], z = F[2 * NPTS + c];
        float f2  = fmaf(x, x, fmaf(y, y, z * z));
        float m2x = -2.f * x, m2y = -2.f * y, m2z = -2.f * z;
        uint32x4 d;
        if (g == 0) {
            float f2l  = f2  - hi16f(f2);
            float m2xl = m2x - hi16f(m2x);
            d[0] = ONE2;
            d[1] = pack2(f2, f2l);
            d[2] = pack2(m2x, m2xl);
            d[3] = pack2(m2x, m2y);
        } else {
            float m2yl = m2y - hi16f(m2y);
            float m2zl = m2z - hi16f(m2z);
            d[0] = pack2(m2yl, m2y);
            d[1] = pack2(m2z, m2zl);
            d[2] = pack2(m2z, 0.f);
            d[3] = 0u;
        }
        return __builtin_bit_cast(bf16x8, d);
    };
    bf16x8 bf0 = build_bf(0), bf1 = build_bf(1);
    bf16x8 bf2 = build_bf(2), bf3 = build_bf(3);

    // A k-scheme g0: [s2h, s2l, 1, 1, xh, xh, xl, yh]
    //            g1: [yh, yl, zh, zh, zl, 0, 0, 0]
    auto build_af = [&](float x, float y, float z) -> bf16x8 {
        float s2 = fmaf(x, x, fmaf(y, y, z * z));
        uint32x4 d;
        if (g == 0) {
            float s2l = s2 - hi16f(s2);
            float xl  = x  - hi16f(x);
            d[0] = pack2(s2, s2l);
            d[1] = ONE2;
            d[2] = pack2(x, x);
            d[3] = pack2(xl, y);
        } else {
            float yl = y - hi16f(y);
            float zl = z - hi16f(z);
            d[0] = pack2(y, yl);
            d[1] = pack2(z, z);
            d[2] = pack2(zl, 0.f);
            d[3] = 0u;
        }
        return __builtin_bit_cast(bf16x8, d);
    };

    f32x16 zero;
    #pragma unroll
    for (int i = 0; i < 16; ++i) zero[i] = 0.f;

    const float INF = __int_as_float(0x7F800000);
    float a0 = INF, a1 = INF, a2 = INF, a3 = INF;

    // min over the 16 regs (16 rows of this lane-half): 8x v_min3
    auto tree = [](float acc, const f32x16& c) -> float {
        float t0 = fminf(fminf(c[0],  c[1]),  c[2]);
        float t1 = fminf(fminf(c[3],  c[4]),  c[5]);
        float t2 = fminf(fminf(c[6],  c[7]),  c[8]);
        float t3 = fminf(fminf(c[9],  c[10]), c[11]);
        float t4 = fminf(fminf(c[12], c[13]), c[14]);
        float r0 = fminf(fminf(t0, t1), t2);
        float r1 = fminf(fminf(t3, t4), c[15]);
        return fminf(fminf(r0, r1), acc);
    };

    const float* S0 = S + (size_t)ns * SROWS + l31;
    const float* S1 = S0 + NPTS;
    const float* S2 = S0 + 2 * NPTS;

    float cx = S0[0], cy = S1[0], cz = S2[0];
    for (int s = 0; s < STEPS; ++s) {
        float nx = 0.f, ny = 0.f, nz = 0.f;
        if (s + 1 < STEPS) {                  // wave-uniform branch
            int o = (s + 1) * 32;
            nx = S0[o]; ny = S1[o]; nz = S2[o];
        }
        bf16x8 af = build_af(cx, cy, cz);
        // <=2 C-tiles live at any point (32 VGPR), each MFMA covered by
        // >=1 tree + 1 MFMA-issue before its first read
        f32x16 c0 = __builtin_amdgcn_mfma_f32_32x32x16_bf16(af, bf0, zero, 0, 0, 0);
        f32x16 c1 = __builtin_amdgcn_mfma_f32_32x32x16_bf16(af, bf1, zero, 0, 0, 0);
        a0 = tree(a0, c0);
        c0 = __builtin_amdgcn_mfma_f32_32x32x16_bf16(af, bf2, zero, 0, 0, 0);
        a1 = tree(a1, c1);
        c1 = __builtin_amdgcn_mfma_f32_32x32x16_bf16(af, bf3, zero, 0, 0, 0);
        a2 = tree(a2, c0);
        a3 = tree(a3, c1);
        cx = nx; cy = ny; cz = nz;
    }

    // combine lane-halves (g=0 regs hold 16 rows, g=1 the complementary 16)
    a0 = fminf(a0, __shfl_xor(a0, 32));
    a1 = fminf(a1, __shfl_xor(a1, 32));
    a2 = fminf(a2, __shfl_xor(a2, 32));
    a3 = fminf(a3, __shfl_xor(a3, 32));

    if (lane < 32) {
        float* dst = part + ((size_t)db * NSPLIT + ns) * NPTS + (size_t)mg * COLS_W;
        dst[l31]      = a0;
        dst[32 + l31] = a1;
        dst[64 + l31] = a2;
        dst[96 + l31] = a3;
    }
}

// min over NSPLIT partials, sqrt, mean, sum both directions
__global__ __launch_bounds__(256) void reduce_k(
    const float* __restrict__ part, float* __restrict__ out)
{
    int tid = blockIdx.x * 256 + threadIdx.x;   // 0..65535
    int db  = tid >> 13;
    int m   = tid & (NPTS - 1);
    const float* base = part + (size_t)db * NSPLIT * NPTS + m;
    float v = base[0];
    #pragma unroll
    for (int nsh = 1; nsh < NSPLIT; ++nsh)
        v = fminf(v, base[(size_t)nsh * NPTS]);
    float d = sqrtf(fmaxf(v, 0.f)) * (1.0f / 32768.0f);
    for (int off = 32; off; off >>= 1) d += __shfl_down(d, off);
    __shared__ float wsum[4];
    if ((threadIdx.x & 63) == 0) wsum[threadIdx.x >> 6] = d;
    __syncthreads();
    if (threadIdx.x == 0) atomicAdd(out, wsum[0] + wsum[1] + wsum[2] + wsum[3]);
}

extern "C" void kernel_launch(void* const* d_in, const int* in_sizes, int n_in,
                              void* d_out, int out_size, void* d_ws, size_t ws_size,
                              hipStream_t stream) {
    const float* pred = (const float*)d_in[0];
    const float* targ = (const float*)d_in[1];
    float* out  = (float*)d_out;
    float* part = (float*)d_ws;   // 8 * NSPLIT * NPTS * 4 = 2 MB

    hipMemsetAsync(d_out, 0, sizeof(float), stream);

    dim3 grid(N_CG, NSPLIT, 8);   // 16 x 8 x 8 = 1024 blocks x 4 waves
    chamfer_v6<<<grid, 256, 0, stream>>>(pred, targ, part);

    reduce_k<<<(8 * NPTS) / 256, 256, 0, stream>>>(part, out);
}